// Round 3
// baseline (499.631 us; speedup 1.0000x reference)
//
#include <hip/hip_runtime.h>
#include <cmath>

// Problem constants: B=64, S=1024, F=256, K=8, L=1017
#define BB 64
#define SS 1024
#define FF 256
#define KK 8
#define LL 1017

typedef __attribute__((ext_vector_type(8))) short bf16x8;
typedef __attribute__((ext_vector_type(4))) float f32x4;

// ---- bf16 helpers (manual, round-to-nearest-even) -------------------------
__device__ __forceinline__ short f2bf(float f) {
  unsigned u = __float_as_uint(f);
  unsigned r = (u + 0x7fffu + ((u >> 16) & 1u)) >> 16;
  return (short)r;
}
__device__ __forceinline__ float bf2f(short s) {
  return __uint_as_float(((unsigned)(unsigned short)s) << 16);
}

// ===========================================================================
// MFMA path
// ===========================================================================

// x [64*1024*256] f32 -> xh, xl bf16 (hi + residual-lo split)
__global__ __launch_bounds__(256) void convert_x_kernel(
    const float* __restrict__ x, short* __restrict__ xh,
    short* __restrict__ xl) {
  const int e0 = (blockIdx.x * 256 + threadIdx.x) * 4;
  if (e0 >= BB * SS * FF) return;
  const float4 v = *(const float4*)&x[e0];
  short h0 = f2bf(v.x), h1 = f2bf(v.y), h2 = f2bf(v.z), h3 = f2bf(v.w);
  short l0 = f2bf(v.x - bf2f(h0)), l1 = f2bf(v.y - bf2f(h1));
  short l2 = f2bf(v.z - bf2f(h2)), l3 = f2bf(v.w - bf2f(h3));
  short4 hv = {h0, h1, h2, h3}, lv = {l0, l1, l2, l3};
  *(short4*)&xh[e0] = hv;
  *(short4*)&xl[e0] = lv;
}

// w [o][i][k] f32 -> fragment-linear packed bf16 hi/lo:
// wpack[e], e = t*8192 + n*32 + (g*8+j), holds B[kk][n] with
// kk = 32t + 8g + j  (k-major ordering: kk = k*256 + i)
__global__ __launch_bounds__(256) void pack_w_kernel(
    const float* __restrict__ w, short* __restrict__ wh,
    short* __restrict__ wl) {
  const int e = blockIdx.x * 256 + threadIdx.x;
  if (e >= 64 * 256 * 32) return;
  const int t = e >> 13;
  const int rem = e & 8191;
  const int n = rem >> 5;
  const int gj = rem & 31;
  const int i = (t & 7) * 32 + gj;
  const int k = t >> 3;
  const float v = w[n * 2048 + i * 8 + k];
  const short h = f2bf(v);
  wh[e] = h;
  wl[e] = f2bf(v - bf2f(h));
}

// Fused implicit-GEMM conv (3-term bf16 split MFMA) + sigmoid/geometric epilogue.
// Grid: 1024 blocks (64 b x 8 ltile x 2 otile), 256 thr = 4 waves (2x2).
__global__ __launch_bounds__(256, 2) void gemm_mfma_kernel(
    const short* __restrict__ xh, const short* __restrict__ xl,
    const short* __restrict__ wh, const short* __restrict__ wl,
    const float* __restrict__ x, const float* __restrict__ cb,
    float* __restrict__ out) {
  __shared__ float ts[64][132];  // t-values staging, 33.8 KB

  const int tid = threadIdx.x;
  const int lane = tid & 63;
  const int wid = tid >> 6;
  const int wm = wid >> 1, wn = wid & 1;
  const int lane_m = lane & 15, lane_g = lane >> 4;

  const int bx = blockIdx.x;
  const int b = bx >> 4;
  const int rem = bx & 15;
  const int l0 = (rem >> 1) * 128;
  const int o0 = (rem & 1) * 128;

  f32x4 acc[4][4];
#pragma unroll
  for (int p = 0; p < 4; ++p)
#pragma unroll
    for (int q = 0; q < 4; ++q) acc[p][q] = (f32x4)0.f;

  const short* xhb = xh + b * (SS * FF);
  const short* xlb = xl + b * (SS * FF);

  int rowb[4];
#pragma unroll
  for (int p = 0; p < 4; ++p) rowb[p] = l0 + wm * 64 + p * 16 + lane_m;
  const int nb = (o0 + wn * 64 + lane_m) * 32 + lane_g * 8;
  const int chanoff = lane_g * 8;

  for (int t = 0; t < 64; ++t) {
    const int k = t >> 3;
    const int io = (t & 7) * 32;
    bf16x8 ah[4], al[4], bh[4], bl[4];
#pragma unroll
    for (int p = 0; p < 4; ++p) {
      int r = rowb[p] + k;
      r = r > (SS - 1) ? (SS - 1) : r;  // only masked rows ever clamp
      const int off = r * FF + io + chanoff;
      ah[p] = *(const bf16x8*)(xhb + off);
      al[p] = *(const bf16x8*)(xlb + off);
    }
    const int wo = t * 8192 + nb;
#pragma unroll
    for (int q = 0; q < 4; ++q) {
      bh[q] = *(const bf16x8*)(wh + wo + q * 512);
      bl[q] = *(const bf16x8*)(wl + wo + q * 512);
    }
#pragma unroll
    for (int p = 0; p < 4; ++p)
#pragma unroll
      for (int q = 0; q < 4; ++q) {
        acc[p][q] = __builtin_amdgcn_mfma_f32_16x16x32_bf16(
            al[p], bh[q], acc[p][q], 0, 0, 0);
        acc[p][q] = __builtin_amdgcn_mfma_f32_16x16x32_bf16(
            ah[p], bl[q], acc[p][q], 0, 0, 0);
        acc[p][q] = __builtin_amdgcn_mfma_f32_16x16x32_bf16(
            ah[p], bh[q], acc[p][q], 0, 0, 0);
      }
  }

  // ---- epilogue: two 64-row phases through LDS ----
  const float* xb = x + b * (SS * FF);
  float* ob = out + (size_t)b * LL * FF;
  const int c0 = (tid & 31) * 4;
  const int rr0 = (tid >> 5) * 8;
  float bias4[4];
  *(float4*)&bias4[0] = *(const float4*)&cb[o0 + c0];

#pragma unroll
  for (int ph = 0; ph < 2; ++ph) {
    if (wm == ph) {
#pragma unroll
      for (int p = 0; p < 4; ++p)
#pragma unroll
        for (int q = 0; q < 4; ++q)
#pragma unroll
          for (int r = 0; r < 4; ++r)
            ts[p * 16 + lane_g * 4 + r][wn * 64 + q * 16 + lane_m] =
                acc[p][q][r];
    }
    __syncthreads();

    const int grow = l0 + ph * 64 + rr0;  // global first out-row this thread
    float4 win[8];                        // sliding x window, rows grow+s
#pragma unroll
    for (int s = 0; s < 7; ++s) {
      int rr = grow + s;
      rr = rr > (SS - 1) ? (SS - 1) : rr;
      win[s] = *(const float4*)&xb[rr * FF + o0 + c0];
    }
#pragma unroll
    for (int r = 0; r < 8; ++r) {
      int rr = grow + r + 7;
      rr = rr > (SS - 1) ? (SS - 1) : rr;  // clamp: only masked rows
      win[(r + 7) & 7] = *(const float4*)&xb[rr * FF + o0 + c0];

      const float4 tv4 = *(const float4*)&ts[rr0 + r][c0];
      const float tvv[4] = {tv4.x, tv4.y, tv4.z, tv4.w};
      float num[4];
#pragma unroll
      for (int c = 0; c < 4; ++c) {
        const float tt = 1.f / (1.f + expf(-(tvv[c] + bias4[c])));
        float d = 1.f;
#pragma unroll
        for (int e = 0; e < 7; ++e) d = fmaf(d, tt, 1.f);
        float n = win[r & 7][c];
#pragma unroll
        for (int i = 1; i < 8; ++i) n = fmaf(n, tt, win[(r + i) & 7][c]);
        num[c] = n / d;
      }
      const int l = grow + r;
      if (l < LL) {
        float4 o4 = {num[0], num[1], num[2], num[3]};
        *(float4*)&ob[(size_t)l * FF + o0 + c0] = o4;
      }
    }
    __syncthreads();  // protect ts before next phase overwrites
  }
}

// ===========================================================================
// fp32 fallback path (hand-verified; used when ws too small)
// ===========================================================================
#define BM 128
#define BN 128
#define ICH 8
#define NCH (FF / ICH)

__global__ __launch_bounds__(256, 2) void transpose_w_kernel(
    const float* __restrict__ w, float* __restrict__ wt) {
  __shared__ float tile[32][33];
  const int r0 = blockIdx.x * 32;
  const int o0 = blockIdx.y * 32;
  const int tx = threadIdx.x;
  const int ty = threadIdx.y;
#pragma unroll
  for (int j = 0; j < 32; j += 8)
    tile[ty + j][tx] = w[(size_t)(o0 + ty + j) * 2048 + (r0 + tx)];
  __syncthreads();
#pragma unroll
  for (int j = 0; j < 32; j += 8)
    wt[(size_t)(r0 + ty + j) * 256 + (o0 + tx)] = tile[tx][ty + j];
}

template <bool USE_WT>
__global__ __launch_bounds__(256, 4) void convfilter_kernel(
    const float* __restrict__ x, const float* __restrict__ wsrc,
    const float* __restrict__ cb, float* __restrict__ out) {
  __shared__ float xs[ICH][136];
  __shared__ float ws[ICH * KK][BN];

  const int tid = threadIdx.x;
  const int bx = blockIdx.x;
  const int b = bx >> 4;
  const int rem = bx & 15;
  const int l0 = (rem >> 1) * BM;
  const int o0 = (rem & 1) * BN;
  const int r0 = (tid >> 5) * 16;
  const int c0 = (tid & 31) * 4;

  float acc[16][4];
#pragma unroll
  for (int i = 0; i < 16; ++i)
#pragma unroll
    for (int c = 0; c < 4; ++c) acc[i][c] = 0.f;

  const float* xb = x + (size_t)b * SS * FF;

  for (int ch = 0; ch < NCH; ++ch) {
    const int i0 = ch * ICH;
#pragma unroll
    for (int j = 0; j < 2; ++j) {
      const int flat = j * 256 + tid;
      if (flat < 272) {
        const int r = flat >> 1;
        const int h = (flat & 1) * 4;
        int sg = l0 + r;
        sg = sg > (SS - 1) ? (SS - 1) : sg;
        const float4 v = *(const float4*)&xb[(size_t)sg * FF + i0 + h];
        xs[h + 0][r] = v.x;
        xs[h + 1][r] = v.y;
        xs[h + 2][r] = v.z;
        xs[h + 3][r] = v.w;
      }
    }
    if (USE_WT) {
#pragma unroll
      for (int j = 0; j < 8; ++j) {
        const int flat = j * 256 + tid;
        const int rr = flat >> 5;
        const int c4 = (flat & 31) * 4;
        *(float4*)&ws[rr][c4] =
            *(const float4*)&wsrc[(size_t)(ch * 64 + rr) * 256 + o0 + c4];
      }
    } else {
#pragma unroll
      for (int j = 0; j < 8; ++j) {
        const int flat = j * 256 + tid;
        const int o = flat >> 4;
        const int q = flat & 15;
        const float4 v =
            *(const float4*)&wsrc[(size_t)(o0 + o) * 2048 + ch * 64 + q * 4];
        ws[q * 4 + 0][o] = v.x;
        ws[q * 4 + 1][o] = v.y;
        ws[q * 4 + 2][o] = v.z;
        ws[q * 4 + 3][o] = v.w;
      }
    }
    __syncthreads();

#pragma unroll 2
    for (int ic = 0; ic < ICH; ++ic) {
      float a[24];
#pragma unroll
      for (int m = 0; m < 6; ++m)
        *(float4*)&a[m * 4] = *(const float4*)&xs[ic][r0 + m * 4];
#pragma unroll
      for (int k = 0; k < KK; ++k) {
        const float4 bv = *(const float4*)&ws[ic * 8 + k][c0];
#pragma unroll
        for (int jr = 0; jr < 16; ++jr) {
          acc[jr][0] = fmaf(a[jr + k], bv.x, acc[jr][0]);
          acc[jr][1] = fmaf(a[jr + k], bv.y, acc[jr][1]);
          acc[jr][2] = fmaf(a[jr + k], bv.z, acc[jr][2]);
          acc[jr][3] = fmaf(a[jr + k], bv.w, acc[jr][3]);
        }
      }
    }
    __syncthreads();
  }

  float biasf[4];
  *(float4*)&biasf[0] = *(const float4*)&cb[o0 + c0];
  float* ob = out + (size_t)b * LL * FF;

#pragma unroll
  for (int g = 0; g < 4; ++g) {
    float xvf[11][4];
#pragma unroll
    for (int m = 0; m < 11; ++m) {
      int sg = l0 + r0 + g * 4 + m;
      sg = sg > (SS - 1) ? (SS - 1) : sg;
      *(float4*)&xvf[m][0] = *(const float4*)&xb[(size_t)sg * FF + o0 + c0];
    }
#pragma unroll
    for (int jj = 0; jj < 4; ++jj) {
      const int jr = g * 4 + jj;
      const int l = l0 + r0 + jr;
      float num[4];
#pragma unroll
      for (int c = 0; c < 4; ++c) {
        const float tv = acc[jr][c] + biasf[c];
        const float t = 1.f / (1.f + expf(-tv));
        float d = 1.f;
#pragma unroll
        for (int e = 0; e < 7; ++e) d = fmaf(d, t, 1.f);
        float n = xvf[jj][c];
#pragma unroll
        for (int i = 1; i < 8; ++i) n = fmaf(n, t, xvf[jj + i][c]);
        num[c] = n / d;
      }
      if (l < LL) {
        float4 o4 = {num[0], num[1], num[2], num[3]};
        *(float4*)&ob[(size_t)l * FF + o0 + c0] = o4;
      }
    }
  }
}

// ===========================================================================
extern "C" void kernel_launch(void* const* d_in, const int* in_sizes, int n_in,
                              void* d_out, int out_size, void* d_ws,
                              size_t ws_size, hipStream_t stream) {
  const float* x = (const float*)d_in[0];   // [64,1024,256] f32
  const float* w = (const float*)d_in[1];   // [256,256,8]   f32
  const float* cb = (const float*)d_in[2];  // [256]         f32
  float* out = (float*)d_out;               // [64,1017,256] f32

  const size_t NX = (size_t)BB * SS * FF;        // 16,777,216
  const size_t NW = (size_t)64 * 256 * 32;       // 524,288
  const size_t mfma_ws = (2 * NX + 2 * NW) * 2;  // 69,206,016 B

  if (d_ws && ws_size >= mfma_ws) {
    short* xh = (short*)d_ws;
    short* xl = xh + NX;
    short* wh = xl + NX;
    short* wl = wh + NW;
    convert_x_kernel<<<(int)(NX / 1024), 256, 0, stream>>>(x, xh, xl);
    pack_w_kernel<<<(int)(NW / 256), 256, 0, stream>>>(w, wh, wl);
    gemm_mfma_kernel<<<1024, 256, 0, stream>>>(xh, xl, wh, wl, x, cb, out);
  } else if (d_ws && ws_size >= 2048ull * 256ull * sizeof(float)) {
    float* wt = (float*)d_ws;
    dim3 tb(32, 8);
    dim3 tg(2048 / 32, 256 / 32);
    transpose_w_kernel<<<tg, tb, 0, stream>>>(w, wt);
    convfilter_kernel<true><<<1024, 256, 0, stream>>>(x, wt, cb, out);
  } else {
    convfilter_kernel<false><<<1024, 256, 0, stream>>>(x, w, cb, out);
  }
}

// Round 5
// 346.213 us; speedup vs baseline: 1.4431x; 1.4431x over previous
//
#include <hip/hip_runtime.h>
#include <cmath>

// Problem constants: B=64, S=1024, F=256, K=8, L=1017
#define BB 64
#define SS 1024
#define FF 256
#define KK 8
#define LL 1017

#define CC 64   // channels staged per chunk
#define RS 136  // rows staged (128 + K-1, padded to 17*8)

typedef __attribute__((ext_vector_type(8))) short bf16x8;
typedef __attribute__((ext_vector_type(8))) short short8v;
typedef __attribute__((ext_vector_type(16))) float f32x16;

__device__ __forceinline__ short f2bf(float f) {
  unsigned u = __float_as_uint(f);
  unsigned r = (u + 0x7fffu + ((u >> 16) & 1u)) >> 16;
  return (short)r;
}
__device__ __forceinline__ float bf2f(short s) {
  return __uint_as_float(((unsigned)(unsigned short)s) << 16);
}

// x f32 -> xh, xl bf16 (hi + residual-lo), 8 elems/thread, 16B stores
__global__ __launch_bounds__(256) void convert_x_kernel(
    const float* __restrict__ x, short* __restrict__ xh,
    short* __restrict__ xl) {
  const int e0 = (blockIdx.x * 256 + threadIdx.x) * 8;
  const float4 v0 = *(const float4*)&x[e0];
  const float4 v1 = *(const float4*)&x[e0 + 4];
  const float vv[8] = {v0.x, v0.y, v0.z, v0.w, v1.x, v1.y, v1.z, v1.w};
  short8v hv, lv;
#pragma unroll
  for (int j = 0; j < 8; ++j) {
    const short h = f2bf(vv[j]);
    hv[j] = h;
    lv[j] = f2bf(vv[j] - bf2f(h));
  }
  *(short8v*)&xh[e0] = hv;
  *(short8v*)&xl[e0] = lv;
}

// w[o][i][k] f32 -> fragment-linear bf16 hi/lo for 32x32x16, k-major kk.
// e = T*4096 + n*16 + (g2*8+j): T = k*16 + i_hi (i = i_hi*16 + g2*8 + j)
__global__ __launch_bounds__(256) void pack_w_kernel(
    const float* __restrict__ w, short* __restrict__ wh,
    short* __restrict__ wl) {
  const int e = blockIdx.x * 256 + threadIdx.x;
  const int T = e >> 12;
  const int n = (e >> 4) & 255;
  const int gj = e & 15;
  const int i = ((T & 15) << 4) + gj;
  const int k = T >> 4;
  const float v = w[n * 2048 + i * 8 + k];
  const short h = f2bf(v);
  wh[e] = h;
  wl[e] = f2bf(v - bf2f(h));
}

// Fused implicit-GEMM conv (3-term bf16 split, 32x32x16 MFMA, LDS-staged A)
// + sigmoid/geometric epilogue. Grid 1024 (64 b x 8 ltile x 2 otile), 4 waves.
__global__ __launch_bounds__(256, 3) void gemm_mfma_kernel(
    const short* __restrict__ xh, const short* __restrict__ xl,
    const short* __restrict__ wh, const short* __restrict__ wl,
    const float* __restrict__ x, const float* __restrict__ cb,
    float* __restrict__ out) {
  // 34816 B: xs_h [136][64] bf16 (17408 B) + xs_l; overlaid by ts[64][132] f32
  __shared__ __align__(16) char smem[2 * RS * CC * 2];
  short* xsh = (short*)smem;
  short* xsl = (short*)(smem + RS * CC * 2);
  float(*ts)[132] = (float(*)[132])smem;

  const int tid = threadIdx.x;
  const int lane = tid & 63;
  const int wid = tid >> 6;
  const int wm = wid >> 1, wn = wid & 1;
  const int l5 = lane & 31, hi = lane >> 5;

  // XCD-aware swizzle (1024 % 8 == 0 -> bijective)
  const int bx0 = blockIdx.x;
  const int bx = (bx0 & 7) * 128 + (bx0 >> 3);
  const int b = bx >> 4;
  const int rem = bx & 15;
  const int l0 = (rem >> 1) * 128;
  const int o0 = (rem & 1) * 128;

  f32x16 acc[2][2];
#pragma unroll
  for (int p = 0; p < 2; ++p)
#pragma unroll
    for (int q = 0; q < 2; ++q) acc[p][q] = (f32x16)0.f;

  const short* xhb = xh + b * (SS * FF);
  const short* xlb = xl + b * (SS * FF);

  const int srow = lane >> 3;  // row within 8-row block (staging)
  const int sslot = lane & 7;  // 16B slot within 128B row (staging)

  for (int c = 0; c < 4; ++c) {
    const int cbase = c * CC;
    __syncthreads();  // previous chunk fully consumed / ts not yet live
    // ---- stage x-window chunk: rows l0..l0+135, chans cbase..cbase+63 ----
    // linear LDS dest + inverse-swizzled global source (rule 21)
    for (int idx = wid; idx < 34; idx += 4) {
      const int arr = idx >= 17 ? 1 : 0;
      const int rb = arr ? idx - 17 : idx;
      const int row = rb * 8 + srow;
      int gr = l0 + row;
      gr = gr > (SS - 1) ? (SS - 1) : gr;  // clamp: only masked rows
      const int slot_swz = sslot ^ (row & 7);
      const short* gsrc =
          (arr ? xlb : xhb) + gr * FF + cbase + slot_swz * 8;
      char* ldst = (arr ? (char*)xsl : (char*)xsh) + rb * 1024;
      __builtin_amdgcn_global_load_lds(
          (const __attribute__((address_space(1))) unsigned*)gsrc,
          (__attribute__((address_space(3))) unsigned*)ldst, 16, 0, 0);
    }
    __syncthreads();  // compiler drains vmcnt(0) before s_barrier

    // ---- compute: 8 k x 4 i2 = 32 MFMA-steps (K=16 each) ----
#pragma unroll
    for (int k = 0; k < 8; ++k) {
#pragma unroll
      for (int i2 = 0; i2 < 4; ++i2) {
        const int T = k * 16 + c * 4 + i2;
        const int i0loc = i2 * 16;
        bf16x8 ah[2], al[2], bhf[2], blf[2];
#pragma unroll
        for (int p = 0; p < 2; ++p) {
          const int row = wm * 64 + p * 32 + l5 + k;
          int byte = row * 128 + (i0loc + hi * 8) * 2;
          byte ^= (row & 7) << 4;  // T2 un-swizzle on read
          ah[p] = *(const bf16x8*)((const char*)xsh + byte);
          al[p] = *(const bf16x8*)((const char*)xsl + byte);
        }
#pragma unroll
        for (int q = 0; q < 2; ++q) {
          const int n = o0 + wn * 64 + q * 32 + l5;
          const int off = T * 4096 + n * 16 + hi * 8;
          bhf[q] = *(const bf16x8*)(wh + off);
          blf[q] = *(const bf16x8*)(wl + off);
        }
#pragma unroll
        for (int p = 0; p < 2; ++p)
#pragma unroll
          for (int q = 0; q < 2; ++q) {
            acc[p][q] = __builtin_amdgcn_mfma_f32_32x32x16_bf16(
                al[p], bhf[q], acc[p][q], 0, 0, 0);
            acc[p][q] = __builtin_amdgcn_mfma_f32_32x32x16_bf16(
                ah[p], blf[q], acc[p][q], 0, 0, 0);
            acc[p][q] = __builtin_amdgcn_mfma_f32_32x32x16_bf16(
                ah[p], bhf[q], acc[p][q], 0, 0, 0);
          }
      }
    }
  }

  // ---- epilogue: 2 phases of 64 rows through ts (overlays xs) ----
  const float* xb = x + b * (SS * FF);
  float* ob = out + (size_t)b * LL * FF;
  const int c0 = (tid & 31) * 4;
  const int rr0 = (tid >> 5) * 8;
  float bias4[4];
  *(float4*)&bias4[0] = *(const float4*)&cb[o0 + c0];

  for (int ph = 0; ph < 2; ++ph) {
    __syncthreads();  // xs reads / previous phase reads complete
    if (wm == ph) {
      // C/D layout (m74/m101): col=lane&31, row=(r&3)+8*(r>>2)+4*(lane>>5)
#pragma unroll
      for (int p = 0; p < 2; ++p)
#pragma unroll
        for (int q = 0; q < 2; ++q)
#pragma unroll
          for (int r = 0; r < 16; ++r)
            ts[p * 32 + (r & 3) + 8 * (r >> 2) + 4 * hi]
              [wn * 64 + q * 32 + l5] = acc[p][q][r];
    }
    __syncthreads();

    const int grow = l0 + ph * 64 + rr0;
    float4 win[8];
#pragma unroll
    for (int s = 0; s < 7; ++s) {
      int rr = grow + s;
      rr = rr > (SS - 1) ? (SS - 1) : rr;
      win[s] = *(const float4*)&xb[rr * FF + o0 + c0];
    }
#pragma unroll
    for (int r = 0; r < 8; ++r) {
      int rr = grow + r + 7;
      rr = rr > (SS - 1) ? (SS - 1) : rr;  // clamp: only masked rows
      win[(r + 7) & 7] = *(const float4*)&xb[rr * FF + o0 + c0];

      const float4 tv4 = *(const float4*)&ts[rr0 + r][c0];
      const float tvv[4] = {tv4.x, tv4.y, tv4.z, tv4.w};
      float num[4];
#pragma unroll
      for (int cq = 0; cq < 4; ++cq) {
        const float tt = 1.f / (1.f + expf(-(tvv[cq] + bias4[cq])));
        float d = 1.f;
#pragma unroll
        for (int e = 0; e < 7; ++e) d = fmaf(d, tt, 1.f);
        float n = win[r & 7][cq];
#pragma unroll
        for (int i = 1; i < 8; ++i) n = fmaf(n, tt, win[(r + i) & 7][cq]);
        num[cq] = n / d;
      }
      const int l = grow + r;
      if (l < LL) {
        float4 o4 = {num[0], num[1], num[2], num[3]};
        *(float4*)&ob[(size_t)l * FF + o0 + c0] = o4;
      }
    }
  }
}

// ===========================================================================
extern "C" void kernel_launch(void* const* d_in, const int* in_sizes, int n_in,
                              void* d_out, int out_size, void* d_ws,
                              size_t ws_size, hipStream_t stream) {
  const float* x = (const float*)d_in[0];   // [64,1024,256] f32
  const float* w = (const float*)d_in[1];   // [256,256,8]   f32
  const float* cb = (const float*)d_in[2];  // [256]         f32
  float* out = (float*)d_out;               // [64,1017,256] f32

  const size_t NX = (size_t)BB * SS * FF;  // 16,777,216
  const size_t NW = 128ull * 4096ull;      // 524,288

  short* xh = (short*)d_ws;
  short* xl = xh + NX;
  short* wh = xl + NX;
  short* wl = wh + NW;

  convert_x_kernel<<<(int)(NX / (256 * 8)), 256, 0, stream>>>(x, xh, xl);
  pack_w_kernel<<<(int)(NW / 256), 256, 0, stream>>>(w, wh, wl);
  gemm_mfma_kernel<<<1024, 256, 0, stream>>>(xh, xl, wh, wl, x, cb, out);
}

// Round 9
// 324.168 us; speedup vs baseline: 1.5413x; 1.0680x over previous
//
#include <hip/hip_runtime.h>
#include <cmath>

// Problem constants: B=64, S=1024, F=256, K=8, L=1017
#define BB 64
#define SS 1024
#define FF 256
#define KK 8
#define LL 1017

#define CC 64            // channels staged per chunk
#define RS 136           // rows staged (128 + K-1, padded to 17*8)
#define BUFSZ (2 * RS * CC * 2)  // one dbuf slot: xsh+xsl = 34816 B

typedef __attribute__((ext_vector_type(8))) short bf16x8;
typedef __attribute__((ext_vector_type(8))) short short8v;
typedef __attribute__((ext_vector_type(16))) float f32x16;

__device__ __forceinline__ short f2bf(float f) {
  unsigned u = __float_as_uint(f);
  unsigned r = (u + 0x7fffu + ((u >> 16) & 1u)) >> 16;
  return (short)r;
}
__device__ __forceinline__ float bf2f(short s) {
  return __uint_as_float(((unsigned)(unsigned short)s) << 16);
}

// x f32 -> xh, xl bf16 (hi + residual-lo), 8 elems/thread, 16B stores
__global__ __launch_bounds__(256) void convert_x_kernel(
    const float* __restrict__ x, short* __restrict__ xh,
    short* __restrict__ xl) {
  const int e0 = (blockIdx.x * 256 + threadIdx.x) * 8;
  const float4 v0 = *(const float4*)&x[e0];
  const float4 v1 = *(const float4*)&x[e0 + 4];
  const float vv[8] = {v0.x, v0.y, v0.z, v0.w, v1.x, v1.y, v1.z, v1.w};
  short8v hv, lv;
#pragma unroll
  for (int j = 0; j < 8; ++j) {
    const short h = f2bf(vv[j]);
    hv[j] = h;
    lv[j] = f2bf(vv[j] - bf2f(h));
  }
  *(short8v*)&xh[e0] = hv;
  *(short8v*)&xl[e0] = lv;
}

// w[o][i][k] f32 -> fragment-linear bf16 hi/lo for 32x32x16, k-major kk.
// e = T*4096 + n*16 + slot : T = k*16 + (i>>4), slot = i&15.
// Coalesced 32B reads (thread = one (n,i)); wave-coalesced 32B write groups.
__global__ __launch_bounds__(256) void pack_w_kernel(
    const float* __restrict__ w, short* __restrict__ wh,
    short* __restrict__ wl) {
  const int n = blockIdx.x;   // 256 blocks
  const int i = threadIdx.x;  // 256 threads
  const float* src = w + n * 2048 + i * 8;
  const float4 a = *(const float4*)src;
  const float4 b = *(const float4*)(src + 4);
  const float vv[8] = {a.x, a.y, a.z, a.w, b.x, b.y, b.z, b.w};
  const int ihi = i >> 4;
  const int slot = i & 15;
#pragma unroll
  for (int k = 0; k < 8; ++k) {
    const int e = (k * 16 + ihi) * 4096 + n * 16 + slot;
    const short h = f2bf(vv[k]);
    wh[e] = h;
    wl[e] = f2bf(vv[k] - bf2f(h));
  }
}

// Stage one 64-channel x-window chunk into one dbuf slot.
// Uniform 9 global_load_lds per wave (idx 17 & 35 are benign duplicates).
// Linear LDS dest + inverse-swizzled global source (rule 21).
__device__ __forceinline__ void stage_chunk(const short* xhb, const short* xlb,
                                            char* bufbase, int cbase, int l0,
                                            int wid, int srow, int sslot) {
#pragma unroll
  for (int jj = 0; jj < 9; ++jj) {
    const int idx = wid + jj * 4;  // 0..35
    const int arr = idx >= 18 ? 1 : 0;
    int rb = arr ? idx - 18 : idx;
    rb = rb > 16 ? 16 : rb;  // pad: duplicate tail block (same data, same dst)
    const int row = rb * 8 + srow;
    int gr = l0 + row;
    gr = gr > (SS - 1) ? (SS - 1) : gr;  // clamp: only masked rows
    const int slot_swz = sslot ^ (row & 7);
    const short* gsrc = (arr ? xlb : xhb) + gr * FF + cbase + slot_swz * 8;
    char* ldst = bufbase + arr * (RS * CC * 2) + rb * 1024;
    __builtin_amdgcn_global_load_lds(
        (const __attribute__((address_space(1))) unsigned*)gsrc,
        (__attribute__((address_space(3))) unsigned*)ldst, 16, 0, 0);
  }
}

// Fused implicit-GEMM conv (3-term bf16 split, 32x32x16 MFMA, dbuf LDS A)
// + sigmoid/geometric epilogue. Grid 1024 (64 b x 8 ltile x 2 otile), 4 waves.
__global__ __launch_bounds__(256, 2) void gemm_mfma_kernel(
    const short* __restrict__ xh, const short* __restrict__ xl,
    const short* __restrict__ wh, const short* __restrict__ wl,
    const float* __restrict__ x, const float* __restrict__ cb,
    float* __restrict__ out) {
  // 69632 B: two dbuf slots of (xsh[136][64] + xsl[136][64]) bf16.
  // ts[64][132] f32 (33792 B) overlays slot 0 in the epilogue.
  __shared__ __align__(16) char smem[2 * BUFSZ];
  float(*ts)[132] = (float(*)[132])smem;

  const int tid = threadIdx.x;
  const int lane = tid & 63;
  const int wid = tid >> 6;
  const int wm = wid >> 1, wn = wid & 1;
  const int l5 = lane & 31, hi = lane >> 5;

  // XCD-aware swizzle (1024 % 8 == 0 -> bijective)
  const int bx0 = blockIdx.x;
  const int bx = (bx0 & 7) * 128 + (bx0 >> 3);
  const int b = bx >> 4;
  const int rem = bx & 15;
  const int l0 = (rem >> 1) * 128;
  const int o0 = (rem & 1) * 128;

  f32x16 acc[2][2];
#pragma unroll
  for (int p = 0; p < 2; ++p)
#pragma unroll
    for (int q = 0; q < 2; ++q) acc[p][q] = (f32x16)0.f;

  const short* xhb = xh + b * (SS * FF);
  const short* xlb = xl + b * (SS * FF);

  const int srow = lane >> 3;  // staging: row within 8-row block
  const int sslot = lane & 7;  // staging: 16B slot within 128B row

  // ---- prologue: stage chunk 0 into slot 0 ----
  stage_chunk(xhb, xlb, smem, 0, l0, wid, srow, sslot);

#pragma unroll
  for (int c = 0; c < 4; ++c) {
    if (c > 0) __builtin_amdgcn_s_barrier();  // prev compute done; buf free
    if (c < 3) {
      stage_chunk(xhb, xlb, smem + ((c + 1) & 1) * BUFSZ, (c + 1) * CC, l0,
                  wid, srow, sslot);
      // chunk c's 9 loads are the oldest; keep chunk c+1's 9 in flight (T4)
      asm volatile("s_waitcnt vmcnt(9)" ::: "memory");
    } else {
      asm volatile("s_waitcnt vmcnt(0)" ::: "memory");
    }
    __builtin_amdgcn_s_barrier();  // all waves' chunk-c data in LDS

    const char* base = smem + (c & 1) * BUFSZ;
    const short* xsh_c = (const short*)base;
    const short* xsl_c = (const short*)(base + RS * CC * 2);

    // ---- compute: 8 k x 4 i2 = 32 MFMA-steps (K=16 each) ----
#pragma unroll
    for (int k = 0; k < 8; ++k) {
#pragma unroll
      for (int i2 = 0; i2 < 4; ++i2) {
        const int T = k * 16 + c * 4 + i2;
        const int i0loc = i2 * 16;
        bf16x8 ah[2], al[2], bhf[2], blf[2];
#pragma unroll
        for (int p = 0; p < 2; ++p) {
          const int row = wm * 64 + p * 32 + l5 + k;
          int byte = row * 128 + (i0loc + hi * 8) * 2;
          byte ^= (row & 7) << 4;  // T2 un-swizzle on read
          ah[p] = *(const bf16x8*)((const char*)xsh_c + byte);
          al[p] = *(const bf16x8*)((const char*)xsl_c + byte);
        }
#pragma unroll
        for (int q = 0; q < 2; ++q) {
          const int n = o0 + wn * 64 + q * 32 + l5;
          const int off = T * 4096 + n * 16 + hi * 8;
          bhf[q] = *(const bf16x8*)(wh + off);
          blf[q] = *(const bf16x8*)(wl + off);
        }
        // 3 passes of 4 independent MFMAs (dependency distance 4)
#pragma unroll
        for (int pq = 0; pq < 4; ++pq)
          acc[pq >> 1][pq & 1] = __builtin_amdgcn_mfma_f32_32x32x16_bf16(
              al[pq >> 1], bhf[pq & 1], acc[pq >> 1][pq & 1], 0, 0, 0);
#pragma unroll
        for (int pq = 0; pq < 4; ++pq)
          acc[pq >> 1][pq & 1] = __builtin_amdgcn_mfma_f32_32x32x16_bf16(
              ah[pq >> 1], blf[pq & 1], acc[pq >> 1][pq & 1], 0, 0, 0);
#pragma unroll
        for (int pq = 0; pq < 4; ++pq)
          acc[pq >> 1][pq & 1] = __builtin_amdgcn_mfma_f32_32x32x16_bf16(
              ah[pq >> 1], bhf[pq & 1], acc[pq >> 1][pq & 1], 0, 0, 0);
      }
    }
  }

  // ---- epilogue: 2 phases of 64 rows through ts (overlays slot 0;
  //      compute(3) read slot 1, so no liveness overlap) ----
  const float* xb = x + b * (SS * FF);
  float* ob = out + (size_t)b * LL * FF;
  const int c0 = (tid & 31) * 4;
  const int rr0 = (tid >> 5) * 8;
  float bias4[4];
  *(float4*)&bias4[0] = *(const float4*)&cb[o0 + c0];

  for (int ph = 0; ph < 2; ++ph) {
    __syncthreads();  // prev phase readers done / main-loop done
    if (wm == ph) {
      // C/D layout (m74/m101): col=lane&31, row=(r&3)+8*(r>>2)+4*(lane>>5)
#pragma unroll
      for (int p = 0; p < 2; ++p)
#pragma unroll
        for (int q = 0; q < 2; ++q)
#pragma unroll
          for (int r = 0; r < 16; ++r)
            ts[p * 32 + (r & 3) + 8 * (r >> 2) + 4 * hi]
              [wn * 64 + q * 32 + l5] = acc[p][q][r];
    }
    __syncthreads();

    const int grow = l0 + ph * 64 + rr0;
    float4 win[8];
#pragma unroll
    for (int s = 0; s < 7; ++s) {
      int rr = grow + s;
      rr = rr > (SS - 1) ? (SS - 1) : rr;
      win[s] = *(const float4*)&xb[rr * FF + o0 + c0];
    }
#pragma unroll
    for (int r = 0; r < 8; ++r) {
      int rr = grow + r + 7;
      rr = rr > (SS - 1) ? (SS - 1) : rr;  // clamp: only masked rows
      win[(r + 7) & 7] = *(const float4*)&xb[rr * FF + o0 + c0];

      const float4 tv4 = *(const float4*)&ts[rr0 + r][c0];
      const float tvv[4] = {tv4.x, tv4.y, tv4.z, tv4.w};
      float num[4];
#pragma unroll
      for (int cq = 0; cq < 4; ++cq) {
        const float tt = 1.f / (1.f + expf(-(tvv[cq] + bias4[cq])));
        float d = 1.f;
#pragma unroll
        for (int e = 0; e < 7; ++e) d = fmaf(d, tt, 1.f);
        float n = win[r & 7][cq];
#pragma unroll
        for (int i = 1; i < 8; ++i) n = fmaf(n, tt, win[(r + i) & 7][cq]);
        num[cq] = n / d;
      }
      const int l = grow + r;
      if (l < LL) {
        float4 o4 = {num[0], num[1], num[2], num[3]};
        *(float4*)&ob[(size_t)l * FF + o0 + c0] = o4;
      }
    }
  }
}

// ===========================================================================
extern "C" void kernel_launch(void* const* d_in, const int* in_sizes, int n_in,
                              void* d_out, int out_size, void* d_ws,
                              size_t ws_size, hipStream_t stream) {
  const float* x = (const float*)d_in[0];   // [64,1024,256] f32
  const float* w = (const float*)d_in[1];   // [256,256,8]   f32
  const float* cb = (const float*)d_in[2];  // [256]         f32
  float* out = (float*)d_out;               // [64,1017,256] f32

  const size_t NX = (size_t)BB * SS * FF;  // 16,777,216
  const size_t NW = 128ull * 4096ull;      // 524,288

  short* xh = (short*)d_ws;
  short* xl = xh + NX;
  short* wh = xl + NX;
  short* wl = wh + NW;

  convert_x_kernel<<<(int)(NX / (256 * 8)), 256, 0, stream>>>(x, xh, xl);
  pack_w_kernel<<<256, 256, 0, stream>>>(w, wh, wl);
  gemm_mfma_kernel<<<1024, 256, 0, stream>>>(xh, xl, wh, wl, x, cb, out);
}